// Round 1
// baseline (766.919 us; speedup 1.0000x reference)
//
#include <hip/hip_runtime.h>

// Problem constants (N,C,H,W) = (4,64,96,96), K=3, dilations {1,3,5}
#define NB 4
#define C 64
#define H 96
#define W 96
#define HW (H * W)
#define CHW (C * H * W)
#define TH 4
#define TW 16
// tiles per image: (96/4)*(96/16) = 24*6 = 144

// ---------------------------------------------------------------------------
// Kernel 1: fused per-pixel kernel generation + dynamic depthwise conv.
// Grid: 4*144*2 blocks (x2 = channel split), 256 threads (4 waves).
// Each wave owns a wave-uniform set of 24 "channels" ch in [0,192):
//   ch = b*64 + c  (b = branch -> dilation 2b+1, c = channel)
// Per thread: one pixel of the 4x16 tile; y-column (64 f32) held in VGPRs;
// gen_w rows read via wave-uniform scalar loads; output written to ws cat
// buffer [N][256][H][W] at channel 64+ch. Channels [0,64) = x passthrough.
// ---------------------------------------------------------------------------
__global__ __launch_bounds__(256) void gen_dynconv_kernel(
    const float* __restrict__ x, const float* __restrict__ y,
    const float* __restrict__ gen_w, const float* __restrict__ gen_b,
    float* __restrict__ cat)
{
    const int sp  = blockIdx.x & 1;        // channel split 0/1
    const int bid = blockIdx.x >> 1;       // 0..575
    const int n   = bid / 144;
    const int rem = bid % 144;
    const int h0  = (rem / 6) * TH;
    const int w0  = (rem % 6) * TW;
    const int lane = threadIdx.x & 63;
    const int wv   = threadIdx.x >> 6;
    const int ph = lane >> 4, pw = lane & 15;
    const int h = h0 + ph, w = w0 + pw;
    const size_t pix = (size_t)h * W + w;

    // y column for this pixel -> 64 VGPRs
    float yv[64];
    const float* yp = y + (size_t)n * CHW + pix;
#pragma unroll
    for (int cc = 0; cc < 64; ++cc) yv[cc] = yp[(size_t)cc * HW];

    // x passthrough into cat channels [0,64) (only split 0 does it)
    if (sp == 0) {
        const float* xp = x + (size_t)n * CHW + pix;
        float* cp = cat + (size_t)n * 4 * CHW + pix;
#pragma unroll
        for (int k = 0; k < 16; ++k) {
            const int c = wv * 16 + k;
            cp[(size_t)c * HW] = xp[(size_t)c * HW];
        }
    }

    // wave-uniform channel base (force SGPR so gen_w reads become s_loads)
    const int ch0 = __builtin_amdgcn_readfirstlane(wv * 48 + sp * 24);

    for (int chg = 0; chg < 24; ++chg) {
        const int ch = ch0 + chg;          // uniform, 0..191
        const int b = ch / 64;             // branch
        const int c = ch % 64;
        const int d = 2 * b + 1;           // dilation 1/3/5

        const float* gw = gen_w + (size_t)ch * 576;  // 9 rows x 64, contiguous
        const float* gb = gen_b + (size_t)ch * 9;

        float ker[9];
#pragma unroll
        for (int idx = 0; idx < 9; ++idx) ker[idx] = gb[idx];

#pragma unroll
        for (int cc = 0; cc < 64; ++cc) {
            const float yc = yv[cc];
#pragma unroll
            for (int idx = 0; idx < 9; ++idx)
                ker[idx] = fmaf(yc, gw[idx * 64 + cc], ker[idx]);
        }

        // dynamic depthwise conv tap sum for this (b,c) at this pixel
        const float* xc = x + (size_t)n * CHW + (size_t)c * HW;
        float r = 0.f;
#pragma unroll
        for (int idx = 0; idx < 9; ++idx) {
            const int i = idx / 3, j = idx % 3;
            const int hh = h + (i - 1) * d;
            const int ww = w + (j - 1) * d;
            if (hh >= 0 && hh < H && ww >= 0 && ww < W)
                r = fmaf(ker[idx], xc[hh * W + ww], r);
        }
        cat[(size_t)n * 4 * CHW + (size_t)(64 + ch) * HW + pix] = r;
    }
}

// ---------------------------------------------------------------------------
// Kernel 2: fuse conv 3x3, Cin=256 (cat), Cout=64, pad 1.
// Grid: 4*144*2 blocks (x2 = co split), 256 threads.
// Block computes a 4x16 pixel tile for 32 of the 64 output channels
// (each wave: 8 co, wave-uniform -> fuse_w via scalar loads).
// cat halo tiles (6x18 per ci) staged in LDS, 16 ci per chunk.
// ---------------------------------------------------------------------------
__global__ __launch_bounds__(256) void fuse_conv_kernel(
    const float* __restrict__ cat, const float* __restrict__ fw,
    const float* __restrict__ fb, float* __restrict__ out)
{
    __shared__ float s[16][108];   // 16 ci x (6 rows x 18 cols) = 6.9 KB

    const int sp  = blockIdx.x & 1;
    const int bid = blockIdx.x >> 1;
    const int n   = bid / 144;
    const int rem = bid % 144;
    const int h0  = (rem / 6) * TH;
    const int w0  = (rem % 6) * TW;
    const int lane = threadIdx.x & 63;
    const int wv   = threadIdx.x >> 6;
    const int ph = lane >> 4, pw = lane & 15;
    const int h = h0 + ph, w = w0 + pw;

    float acc[8];
#pragma unroll
    for (int k = 0; k < 8; ++k) acc[k] = 0.f;

    const int co0 = __builtin_amdgcn_readfirstlane(sp * 32 + wv * 8);

    for (int ci0 = 0; ci0 < 256; ci0 += 16) {
        __syncthreads();
        // stage 16 ci halo tiles (6x18 each)
        for (int e = threadIdx.x; e < 16 * 108; e += 256) {
            const int ci_l = e / 108;
            const int r2 = e % 108;
            const int rr = r2 / 18, cc2 = r2 % 18;
            const int hh = h0 - 1 + rr, ww = w0 - 1 + cc2;
            float v = 0.f;
            if (hh >= 0 && hh < H && ww >= 0 && ww < W)
                v = cat[(size_t)n * 4 * CHW + (size_t)(ci0 + ci_l) * HW
                        + (size_t)hh * W + ww];
            s[ci_l][r2] = v;
        }
        __syncthreads();

        for (int ci_l = 0; ci_l < 16; ++ci_l) {
            float t[9];
#pragma unroll
            for (int idx = 0; idx < 9; ++idx) {
                const int i = idx / 3, j = idx % 3;
                t[idx] = s[ci_l][(ph + i) * 18 + (pw + j)];
            }
            const float* wrow = fw + ((size_t)co0 * 256 + (size_t)(ci0 + ci_l)) * 9;
#pragma unroll
            for (int k = 0; k < 8; ++k) {
                const float* wk = wrow + (size_t)k * 256 * 9;
#pragma unroll
                for (int idx = 0; idx < 9; ++idx)
                    acc[k] = fmaf(wk[idx], t[idx], acc[k]);
            }
        }
    }

#pragma unroll
    for (int k = 0; k < 8; ++k) {
        const int co = co0 + k;
        out[(size_t)n * CHW + (size_t)co * HW + (size_t)h * W + w]
            = acc[k] + fb[co];
    }
}

// ---------------------------------------------------------------------------
extern "C" void kernel_launch(void* const* d_in, const int* in_sizes, int n_in,
                              void* d_out, int out_size, void* d_ws, size_t ws_size,
                              hipStream_t stream) {
    const float* x      = (const float*)d_in[0];
    const float* y      = (const float*)d_in[1];
    const float* gen_w  = (const float*)d_in[2];
    const float* gen_b  = (const float*)d_in[3];
    const float* fuse_w = (const float*)d_in[4];
    const float* fuse_b = (const float*)d_in[5];
    float* out = (float*)d_out;
    float* cat = (float*)d_ws;   // [4][256][96][96] f32 = 37.75 MB

    gen_dynconv_kernel<<<NB * 144 * 2, 256, 0, stream>>>(x, y, gen_w, gen_b, cat);
    fuse_conv_kernel<<<NB * 144 * 2, 256, 0, stream>>>(cat, fuse_w, fuse_b, out);
}

// Round 3
// 531.761 us; speedup vs baseline: 1.4422x; 1.4422x over previous
//
#include <hip/hip_runtime.h>

// Problem constants (N,C,H,W) = (4,64,96,96), K=3, dilations {1,3,5}
#define NB 4
#define C 64
#define H 96
#define W 96
#define HW (H * W)
#define CHW (C * H * W)
#define TW 16

// ---------------------------------------------------------------------------
// Kernel 1: fused per-pixel kernel generation + dynamic depthwise conv.
// Grid: 4*144*2 blocks (x2 = channel split), 256 threads (4 waves).
// Tile: 4x16 pixels. y tile staged in LDS as [cc/4][pix][cc%4] so the GEMM
// inner loop is ds_read_b128 (lane*16B, conflict-free) + v_fmac with
// wave-uniform s_load gen_w operands. 3 channels per pass (27 accumulators,
// all statically indexed -> registers).
// ---------------------------------------------------------------------------
__global__ __launch_bounds__(256) void gen_dynconv_kernel(
    const float* __restrict__ x, const float* __restrict__ y,
    const float* __restrict__ gen_w, const float* __restrict__ gen_b,
    float* __restrict__ cat)
{
    __shared__ float ys[16][64][4];   // 16 KB: [cc>>2][pixel][cc&3]

    const int sp  = blockIdx.x & 1;        // channel split 0/1
    const int bid = blockIdx.x >> 1;       // 0..575
    const int n   = bid / 144;
    const int rem = bid % 144;
    const int h0  = (rem / 6) * 4;
    const int w0  = (rem % 6) * TW;
    const int tid  = threadIdx.x;
    const int lane = tid & 63;
    const int wv   = tid >> 6;
    const int ph = lane >> 4, pw = lane & 15;
    const int h = h0 + ph, w = w0 + pw;
    const int pix = h * W + w;

    // ---- stage y tile: 64 cc x 64 pixels -> LDS ----
#pragma unroll
    for (int it = 0; it < 16; ++it) {
        const int e = tid + it * 256;
        const int cc = e >> 6, p = e & 63;
        const int hh = h0 + (p >> 4), ww = w0 + (p & 15);
        ys[cc >> 2][p][cc & 3] =
            y[n * CHW + cc * HW + hh * W + ww];
    }

    // ---- x passthrough into cat channels [0,64) (split 0 only) ----
    if (sp == 0) {
        const float* xp = x + n * CHW + pix;
        float* cp = cat + n * 4 * CHW + pix;
#pragma unroll
        for (int k = 0; k < 16; ++k) {
            const int c = wv * 16 + k;
            cp[c * HW] = xp[c * HW];
        }
    }

    __syncthreads();

    // wave-uniform channel base
    const int ch_base = __builtin_amdgcn_readfirstlane(wv * 48 + sp * 24);

    for (int g = 0; g < 24; g += 3) {
        const int chg = ch_base + g;

        float ker[3][9];
#pragma unroll
        for (int cp = 0; cp < 3; ++cp) {
            const float* gb = gen_b + (chg + cp) * 9;
#pragma unroll
            for (int idx = 0; idx < 9; ++idx) ker[cp][idx] = gb[idx];
        }

        const float* gw0 = gen_w + (size_t)chg * 576;   // 3 rows of [9][64]

        for (int cc4 = 0; cc4 < 16; ++cc4) {
            const float4 yv =
                *reinterpret_cast<const float4*>(&ys[cc4][lane][0]);
#pragma unroll
            for (int cp = 0; cp < 3; ++cp) {
                const float* gw = gw0 + cp * 576 + cc4 * 4;
#pragma unroll
                for (int idx = 0; idx < 9; ++idx) {
                    ker[cp][idx] = fmaf(yv.x, gw[idx * 64 + 0], ker[cp][idx]);
                    ker[cp][idx] = fmaf(yv.y, gw[idx * 64 + 1], ker[cp][idx]);
                    ker[cp][idx] = fmaf(yv.z, gw[idx * 64 + 2], ker[cp][idx]);
                    ker[cp][idx] = fmaf(yv.w, gw[idx * 64 + 3], ker[cp][idx]);
                }
            }
        }

        // dynamic depthwise conv taps + store
#pragma unroll
        for (int cp = 0; cp < 3; ++cp) {
            const int ch = chg + cp;
            const int b = ch >> 6;
            const int c = ch & 63;
            const int d = 2 * b + 1;
            const float* xc = x + n * CHW + c * HW;
            float r = 0.f;
#pragma unroll
            for (int idx = 0; idx < 9; ++idx) {
                const int i = idx / 3, j = idx % 3;
                const int hh = h + (i - 1) * d;
                const int ww = w + (j - 1) * d;
                if (hh >= 0 && hh < H && ww >= 0 && ww < W)
                    r = fmaf(ker[cp][idx], xc[hh * W + ww], r);
            }
            cat[n * 4 * CHW + (64 + ch) * HW + pix] = r;
        }
    }
}

// ---------------------------------------------------------------------------
// Kernel 2: fuse conv 3x3, Cin=256 (cat), Cout=64, pad 1.
// Grid: 4*72*2 blocks (x2 = co split), 256 threads (4 waves).
// Tile: 8x16 pixels, 2 vertically-adjacent pixels per thread -> 12 LDS tap
// reads feed 144 FMAs per ci. LDS row stride padded to 20 floats -> uniform
// 2-way bank access (free). Each wave: 8 wave-uniform co (fuse_w via s_load).
// ---------------------------------------------------------------------------
__global__ __launch_bounds__(256) void fuse_conv_kernel(
    const float* __restrict__ cat, const float* __restrict__ fw,
    const float* __restrict__ fb, float* __restrict__ out)
{
    __shared__ float s[16][200];   // 16 ci x (10 rows x stride 20) = 12.8 KB

    const int sp  = blockIdx.x & 1;
    const int bid = blockIdx.x >> 1;       // 0..287
    const int n   = bid / 72;
    const int rem = bid % 72;
    const int h0  = (rem / 6) * 8;
    const int w0  = (rem % 6) * TW;
    const int tid  = threadIdx.x;
    const int lane = tid & 63;
    const int wv   = tid >> 6;
    const int ph = lane >> 4, pw = lane & 15;
    const int hA = h0 + 2 * ph;            // pixel A row
    const int w  = w0 + pw;

    float accA[8], accB[8];
#pragma unroll
    for (int k = 0; k < 8; ++k) { accA[k] = 0.f; accB[k] = 0.f; }

    const int co0 = __builtin_amdgcn_readfirstlane(sp * 32 + wv * 8);

    for (int ci0 = 0; ci0 < 256; ci0 += 16) {
        __syncthreads();
        // stage 16 ci halo tiles (10 rows x 18 cols each)
        for (int e = tid; e < 16 * 180; e += 256) {
            const int ci_l = e / 180;
            const int r2 = e % 180;
            const int rr = r2 / 18, cc2 = r2 % 18;
            const int hh = h0 - 1 + rr, ww = w0 - 1 + cc2;
            float v = 0.f;
            if (hh >= 0 && hh < H && ww >= 0 && ww < W)
                v = cat[n * 4 * CHW + (ci0 + ci_l) * HW + hh * W + ww];
            s[ci_l][rr * 20 + cc2] = v;
        }
        __syncthreads();

        for (int ci_l = 0; ci_l < 16; ++ci_l) {
            float t[4][3];
#pragma unroll
            for (int r = 0; r < 4; ++r)
#pragma unroll
                for (int j = 0; j < 3; ++j)
                    t[r][j] = s[ci_l][(2 * ph + r) * 20 + pw + j];

            const float* wrow = fw + (co0 * 256 + ci0 + ci_l) * 9;
#pragma unroll
            for (int k = 0; k < 8; ++k) {
                const float* wk = wrow + k * 256 * 9;
#pragma unroll
                for (int idx = 0; idx < 9; ++idx) {
                    const int i = idx / 3, j = idx % 3;
                    accA[k] = fmaf(wk[idx], t[i][j], accA[k]);
                    accB[k] = fmaf(wk[idx], t[i + 1][j], accB[k]);
                }
            }
        }
    }

#pragma unroll
    for (int k = 0; k < 8; ++k) {
        const int co = co0 + k;
        const float bias = fb[co];
        out[n * CHW + co * HW + hA * W + w]       = accA[k] + bias;
        out[n * CHW + co * HW + (hA + 1) * W + w] = accB[k] + bias;
    }
}

// ---------------------------------------------------------------------------
extern "C" void kernel_launch(void* const* d_in, const int* in_sizes, int n_in,
                              void* d_out, int out_size, void* d_ws, size_t ws_size,
                              hipStream_t stream) {
    const float* x      = (const float*)d_in[0];
    const float* y      = (const float*)d_in[1];
    const float* gen_w  = (const float*)d_in[2];
    const float* gen_b  = (const float*)d_in[3];
    const float* fuse_w = (const float*)d_in[4];
    const float* fuse_b = (const float*)d_in[5];
    float* out = (float*)d_out;
    float* cat = (float*)d_ws;   // [4][256][96][96] f32 = 37.75 MB

    gen_dynconv_kernel<<<NB * 144 * 2, 256, 0, stream>>>(x, y, gen_w, gen_b, cat);
    fuse_conv_kernel<<<NB * 72 * 2, 256, 0, stream>>>(cat, fuse_w, fuse_b, out);
}

// Round 4
// 232.473 us; speedup vs baseline: 3.2990x; 2.2874x over previous
//
#include <hip/hip_runtime.h>

// (N,C,H,W) = (4,64,96,96), K=3, dilations {1,3,5}. Full-MFMA fp16 rewrite.
typedef _Float16 f16;
typedef _Float16 f16x8 __attribute__((ext_vector_type(8)));
typedef float f32x4 __attribute__((ext_vector_type(4)));

#define H 96
#define W 96
#define HWv (H * W)
#define PREC 9604              // padded records per image (98*98)
// ws layout: catp (f16 NHWC, padded 98x98, 512B/record) | gwp | fwp
#define GWP_OFF  19668992      // = 4*9604*512
#define FWP_OFF  19890176      // = GWP_OFF + 216*1024
// total ws use: 20,185,088 B < 37.75 MB known-safe

__device__ __forceinline__ size_t prec_rec(int n, int h, int w) {
    return (size_t)n * PREC + (size_t)(h + 1) * 98 + (w + 1);
}

// ---------------------------------------------------------------------------
// K0: pack gen_w -> gwp A-frags (f16), fuse_w -> fwp A-frags (f16),
//     zero catp padded borders. A-frag: lane&15 = M row, k = (lane>>4)*8+j.
// ---------------------------------------------------------------------------
__global__ __launch_bounds__(256) void prep_kernel(
    const float* __restrict__ gen_w, const float* __restrict__ fuse_w,
    unsigned char* __restrict__ ws)
{
    const int bid = blockIdx.x, tid = threadIdx.x;
    if (bid < 128) {
        const int gid = bid * 256 + tid;
        const int lane = gid & 63;
        if (gid < 18432) {                      // fwp: frag (cot,tap,s)
            const int rest = gid >> 6;          // 0..287 = (cot*9+tap)*8+s
            const int s = rest & 7;
            const int rest2 = rest >> 3;        // cot*9+tap
            const int tap = rest2 % 9, cot = rest2 / 9;
            const int co = cot * 16 + (lane & 15);
            const int ci0 = s * 32 + (lane >> 4) * 8;
            f16x8 v;
#pragma unroll
            for (int j = 0; j < 8; ++j)
                v[j] = (f16)fuse_w[(co * 256 + ci0 + j) * 9 + tap];
            reinterpret_cast<f16x8*>(ws + FWP_OFF)[rest * 64 + lane] = v;
        } else if (gid < 32256) {               // gwp: frag (T,s)
            const int fid = gid - 18432;
            const int lane2 = fid & 63;
            const int rest = fid >> 6;          // 0..215 = T*2+s
            const int T = rest >> 1, s = rest & 1;
            const int o = T * 16 + (lane2 & 15);
            const int cc0 = s * 32 + (lane2 >> 4) * 8;
            f16x8 v;
#pragma unroll
            for (int j = 0; j < 8; ++j)
                v[j] = (f16)gen_w[o * 64 + cc0 + j];
            reinterpret_cast<f16x8*>(ws + GWP_OFF)[rest * 64 + lane2] = v;
        }
    } else {
        // zero padded borders: 4 images * 388 border records * 32 chunks
        const int idx0 = (bid - 128) * 256 + tid;
        for (int k = idx0; k < 49664; k += 32768) {
            const int rec = k >> 5, chunk = k & 31;
            const int n = rec / 388, rr = rec % 388;
            int r, c;
            if (rr < 196) { r = (rr < 98) ? 0 : 97; c = rr % 98; }
            else { const int k2 = rr - 196; c = (k2 < 96) ? 0 : 97; r = 1 + (k2 % 96); }
            const int4 z{0, 0, 0, 0};
            *reinterpret_cast<int4*>(
                ws + ((size_t)n * PREC + (size_t)r * 98 + c) * 512 + chunk * 16) = z;
        }
    }
}

// ---------------------------------------------------------------------------
// K1: kernel-generation GEMM (MFMA f16) + dynamic depthwise conv epilogue.
// Grid 576 (n,tile), 256 thr / 4 waves. px-tile 4x16 = 64 (4 N-blocks).
// Waves split M (9 tiles per 144-o group: {3,2,2,2}). B (y) frags in regs.
// Also writes x (f16) into catp ci[0,64).
// ---------------------------------------------------------------------------
__global__ __launch_bounds__(256, 2) void gen_dyn_kernel(
    const float* __restrict__ x, const float* __restrict__ y,
    const float* __restrict__ gen_b, unsigned char* __restrict__ ws)
{
    // [0,8192) yls | [8192,47360) klds 144x68 f32 (phase-A xls reuse) | [47360,49408) cslice
    __shared__ __align__(16) unsigned char smem[49408];
    const int tid = threadIdx.x, lane = tid & 63, wv = tid >> 6;
    const int q = lane >> 4;
    const int bid = blockIdx.x;
    const int n = bid / 144, tile = bid % 144;
    const int h0 = (tile / 6) * 4, w0 = (tile % 6) * 16;

    // ---- phase A: x tile -> catp ci[0,64) via swizzled LDS transpose ----
    {
        unsigned char* xls = smem + 8192;
#pragma unroll
        for (int it = 0; it < 16; ++it) {
            const int e = tid + it * 256;
            const int cc = e >> 6, p = e & 63;
            const float v = x[(size_t)(n * 64 + cc) * HWv + (h0 + (p >> 4)) * W + w0 + (p & 15)];
            *reinterpret_cast<f16*>(xls + ((p * 128 + cc * 2) ^ ((p & 7) << 4))) = (f16)v;
        }
        __syncthreads();
#pragma unroll
        for (int it = 0; it < 2; ++it) {
            const int px = it * 32 + (tid >> 3), c8 = tid & 7;
            const int4 v = *reinterpret_cast<const int4*>(
                xls + px * 128 + ((c8 ^ (px & 7)) << 4));
            const size_t rec = prec_rec(n, h0 + (px >> 4), w0 + (px & 15));
            *reinterpret_cast<int4*>(ws + rec * 512 + c8 * 16) = v;
        }
        __syncthreads();
    }
    // ---- phase B: y tile -> yls (f16 [px][cc], XOR-swizzled) ----
#pragma unroll
    for (int it = 0; it < 16; ++it) {
        const int e = tid + it * 256;
        const int cc = e >> 6, p = e & 63;
        const float v = y[(size_t)(n * 64 + cc) * HWv + (h0 + (p >> 4)) * W + w0 + (p & 15)];
        *reinterpret_cast<f16*>(smem + ((p * 128 + cc * 2) ^ ((p & 7) << 4))) = (f16)v;
    }
    __syncthreads();

    // ---- B fragments (y) -> registers, kept whole kernel ----
    f16x8 Bf[4][2];
#pragma unroll
    for (int pb = 0; pb < 4; ++pb)
#pragma unroll
        for (int s = 0; s < 2; ++s) {
            const int px = pb * 16 + (lane & 15);
            Bf[pb][s] = *reinterpret_cast<const f16x8*>(
                smem + ((px * 128 + s * 64 + q * 16) ^ ((px & 7) << 4)));
        }

    const f16x8* gwp = reinterpret_cast<const f16x8*>(ws + GWP_OFF);
    float* klds = reinterpret_cast<float*>(smem + 8192);   // [144][68] f32
    const int mb = (wv == 0) ? 0 : (wv == 1) ? 3 : (wv == 2) ? 5 : 7;
    const int mc = (wv == 0) ? 3 : 2;
    const bool interior = (h0 >= 8) && (h0 <= 84) && (w0 >= 16) && (w0 <= 64);

    for (int g = 0; g < 12; ++g) {
        // MFMA: kernels for o in [g*144, g*144+144) -> klds[o_loc][px]
        for (int m = 0; m < mc; ++m) {
            const int T = g * 9 + mb + m;
            const f16x8 A0 = gwp[(T * 2 + 0) * 64 + lane];
            const f16x8 A1 = gwp[(T * 2 + 1) * 64 + lane];
            const f32x4 gb4 = *reinterpret_cast<const f32x4*>(gen_b + T * 16 + q * 4);
            const int o0 = (mb + m) * 16 + q * 4;
#pragma unroll
            for (int pb = 0; pb < 4; ++pb) {
                f32x4 a = {0.f, 0.f, 0.f, 0.f};
                a = __builtin_amdgcn_mfma_f32_16x16x32_f16(A0, Bf[pb][0], a, 0, 0, 0);
                a = __builtin_amdgcn_mfma_f32_16x16x32_f16(A1, Bf[pb][1], a, 0, 0, 0);
                const int px = pb * 16 + (lane & 15);
                klds[(o0 + 0) * 68 + px] = a[0] + gb4[0];
                klds[(o0 + 1) * 68 + px] = a[1] + gb4[1];
                klds[(o0 + 2) * 68 + px] = a[2] + gb4[2];
                klds[(o0 + 3) * 68 + px] = a[3] + gb4[3];
            }
        }
        __syncthreads();
        // epilogue: dynamic conv for ch in [g*16, g*16+16), 4 px per thread
        {
            const int chl = tid >> 4, px4 = tid & 15;
            const int hloc = px4 >> 2, wl4 = (px4 & 3) * 4;
            const int ch = g * 16 + chl;
            const int bb = ch >> 6, c = ch & 63, d = 2 * bb + 1;
            const int h = h0 + hloc, w = w0 + wl4;
            const float* xc = x + (size_t)(n * 64 + c) * HWv;
            f32x4 racc = {0.f, 0.f, 0.f, 0.f};
            if (interior) {
#pragma unroll
                for (int tap = 0; tap < 9; ++tap) {
                    const f32x4 k4 = *reinterpret_cast<const f32x4*>(
                        klds + (chl * 9 + tap) * 68 + hloc * 16 + wl4);
                    const int hh = h + (tap / 3 - 1) * d;
                    const float* xr = xc + hh * W + (w + (tap % 3 - 1) * d);
                    racc[0] = fmaf(k4[0], xr[0], racc[0]);
                    racc[1] = fmaf(k4[1], xr[1], racc[1]);
                    racc[2] = fmaf(k4[2], xr[2], racc[2]);
                    racc[3] = fmaf(k4[3], xr[3], racc[3]);
                }
            } else {
#pragma unroll
                for (int tap = 0; tap < 9; ++tap) {
                    const f32x4 k4 = *reinterpret_cast<const f32x4*>(
                        klds + (chl * 9 + tap) * 68 + hloc * 16 + wl4);
                    const int hh = h + (tap / 3 - 1) * d;
                    if (hh >= 0 && hh < H) {
                        const int wwb = w + (tap % 3 - 1) * d;
#pragma unroll
                        for (int k = 0; k < 4; ++k) {
                            const int wk = wwb + k;
                            if (wk >= 0 && wk < W)
                                racc[k] = fmaf(k4[k], xc[hh * W + wk], racc[k]);
                        }
                    }
                }
            }
            unsigned char* cs = smem + 47360;
#pragma unroll
            for (int k = 0; k < 4; ++k) {
                const int px = hloc * 16 + wl4 + k;
                *reinterpret_cast<f16*>(
                    cs + ((px * 32 + chl * 2) ^ (((px >> 2) & 3) << 3))) = (f16)racc[k];
            }
        }
        __syncthreads();
        // flush cslice -> catp ci [64+g*16, 64+g*16+16), 32B/px coalesced
        {
            const unsigned char* cs = smem + 47360;
            const int px = tid >> 2, chunk = tid & 3;
            const uint2 v = *reinterpret_cast<const uint2*>(
                cs + ((px * 32 + chunk * 8) ^ (((px >> 2) & 3) << 3)));
            const size_t rec = prec_rec(n, h0 + (px >> 4), w0 + (px & 15));
            *reinterpret_cast<uint2*>(ws + rec * 512 + 128 + g * 32 + chunk * 8) = v;
        }
        // next group's klds writes may overlap flush (disjoint LDS regions)
    }
}

// ---------------------------------------------------------------------------
// K2: fuse conv 3x3 Cin=256 Cout=64 as MFMA implicit GEMM (f16).
// Grid 576 (n,tile), 256 thr / 4 waves. Waves split K (64 ci each).
// Halo tile (6x18 px, 256 ci) staged to swizzled LDS; A-frags from fwp global.
// Serial cross-wave reduction, then bias+store.
// ---------------------------------------------------------------------------
__global__ __launch_bounds__(256, 2) void fuse_mfma_kernel(
    const unsigned char* __restrict__ ws, const float* __restrict__ fb,
    float* __restrict__ out)
{
    __shared__ __align__(16) unsigned char smem[71680];  // 55296 halo | 16384 red
    const int tid = threadIdx.x, lane = tid & 63, wv = tid >> 6;
    const int q = lane >> 4;
    const int bid = blockIdx.x;
    const int n = bid / 144, tile = bid % 144;
    const int h0 = (tile / 6) * 4, w0 = (tile % 6) * 16;

    // ---- stage halo (padded rows h0..h0+5, cols w0..w0+17) into swizzled LDS ----
    for (int L = tid * 16; L < 55296; L += 4096) {
        const int hpx = L >> 9;
        const int r = hpx / 18, c = hpx - r * 18;
        const int inrec = L & 511;
        const int4 v = *reinterpret_cast<const int4*>(
            ws + ((size_t)n * PREC + (size_t)(h0 + r) * 98 + (w0 + c)) * 512 + inrec);
        *reinterpret_cast<int4*>(smem + (L ^ (((L >> 9) & 7) << 4))) = v;
    }
    __syncthreads();

    f32x4 acc[4][4];
#pragma unroll
    for (int i = 0; i < 4; ++i)
#pragma unroll
        for (int j = 0; j < 4; ++j) acc[i][j] = {0.f, 0.f, 0.f, 0.f};

    const f16x8* fwp = reinterpret_cast<const f16x8*>(ws + FWP_OFF);
    for (int tap = 0; tap < 9; ++tap) {
        const int rbase = tap / 3, cadd = tap % 3;
#pragma unroll
        for (int sl = 0; sl < 2; ++sl) {
            const int s = wv * 2 + sl;
            f16x8 Af[4];
#pragma unroll
            for (int cot = 0; cot < 4; ++cot)
                Af[cot] = fwp[((cot * 9 + tap) * 8 + s) * 64 + lane];
            f16x8 Bfr[4];
#pragma unroll
            for (int pb = 0; pb < 4; ++pb) {
                const int hpx = (pb + rbase) * 18 + (lane & 15) + cadd;
                Bfr[pb] = *reinterpret_cast<const f16x8*>(
                    smem + ((hpx * 512 + s * 64 + q * 16) ^ ((hpx & 7) << 4)));
            }
#pragma unroll
            for (int pb = 0; pb < 4; ++pb)
#pragma unroll
                for (int cot = 0; cot < 4; ++cot)
                    acc[pb][cot] = __builtin_amdgcn_mfma_f32_16x16x32_f16(
                        Af[cot], Bfr[pb], acc[pb][cot], 0, 0, 0);
        }
    }

    // ---- serial cross-wave reduction in LDS (region reused after compute) ----
    float* red = reinterpret_cast<float*>(smem + 55296);   // [16][64] f32x4
    __syncthreads();
    if (wv == 3) {
#pragma unroll
        for (int i = 0; i < 16; ++i)
            *reinterpret_cast<f32x4*>(red + (i * 64 + lane) * 4) = acc[i >> 2][i & 3];
    }
    __syncthreads();
    if (wv == 2) {
#pragma unroll
        for (int i = 0; i < 16; ++i) {
            f32x4* p = reinterpret_cast<f32x4*>(red + (i * 64 + lane) * 4);
            *p = *p + acc[i >> 2][i & 3];
        }
    }
    __syncthreads();
    if (wv == 1) {
#pragma unroll
        for (int i = 0; i < 16; ++i) {
            f32x4* p = reinterpret_cast<f32x4*>(red + (i * 64 + lane) * 4);
            *p = *p + acc[i >> 2][i & 3];
        }
    }
    __syncthreads();
    if (wv == 0) {
#pragma unroll
        for (int i = 0; i < 16; ++i) {
            f32x4* p = reinterpret_cast<f32x4*>(red + (i * 64 + lane) * 4);
            *p = *p + acc[i >> 2][i & 3];
        }
    }
    __syncthreads();

    // ---- bias + store (all 256 threads) ----
    const int l = tid & 63, i0 = tid >> 6;
#pragma unroll
    for (int ii = 0; ii < 4; ++ii) {
        const int i = i0 + ii * 4;
        const int pb = i >> 2, cot = i & 3;
        const f32x4 v = *reinterpret_cast<const f32x4*>(red + (i * 64 + l) * 4);
        const int co0 = cot * 16 + (l >> 4) * 4;
        const f32x4 fb4 = *reinterpret_cast<const f32x4*>(fb + co0);
        const int hh = h0 + pb, ww = w0 + (l & 15);
#pragma unroll
        for (int r = 0; r < 4; ++r)
            out[(size_t)(n * 64 + co0 + r) * HWv + hh * W + ww] = v[r] + fb4[r];
    }
}

// ---------------------------------------------------------------------------
extern "C" void kernel_launch(void* const* d_in, const int* in_sizes, int n_in,
                              void* d_out, int out_size, void* d_ws, size_t ws_size,
                              hipStream_t stream) {
    const float* x      = (const float*)d_in[0];
    const float* y      = (const float*)d_in[1];
    const float* gen_w  = (const float*)d_in[2];
    const float* gen_b  = (const float*)d_in[3];
    const float* fuse_w = (const float*)d_in[4];
    const float* fuse_b = (const float*)d_in[5];
    unsigned char* ws = (unsigned char*)d_ws;

    prep_kernel<<<256, 256, 0, stream>>>(gen_w, fuse_w, ws);
    gen_dyn_kernel<<<576, 256, 0, stream>>>(x, y, gen_b, ws);
    fuse_mfma_kernel<<<576, 256, 0, stream>>>(ws, fuse_b, (float*)d_out);
}